// Round 7
// baseline (331.222 us; speedup 1.0000x reference)
//
#include <hip/hip_runtime.h>
#include <math.h>

// MultiHeadAttn bf16-MFMA pipeline for MI355X (gfx950), round 6 (resubmit).
// r6: attn QBLK 256 (mi=4, halves per-iter overhead), paired-bx CU balance,
// T5 setprio around attn MFMA clusters, T1 XCD-chunk swizzle on GEMMs.

typedef __attribute__((ext_vector_type(8))) short short8;   // 8 bf16 = 4 VGPR
typedef __attribute__((ext_vector_type(4))) short s16x4;    // 4 bf16 = 2 VGPR
typedef __attribute__((ext_vector_type(4))) float f32x4;    // MFMA C/D
typedef __attribute__((ext_vector_type(4))) unsigned short u16x4;
typedef __attribute__((ext_vector_type(2))) unsigned int u32x2;

constexpr int B  = 4;
constexpr int S  = 2048;
constexpr int H  = 16;
constexpr int DM = 1024;
constexpr int M  = B * S;  // 8192

__device__ __forceinline__ unsigned short f2bf(float f) {
    union { float f; unsigned u; } v; v.f = f;
    unsigned r = v.u + 0x7FFFu + ((v.u >> 16) & 1u);  // RNE, finite inputs
    return (unsigned short)(r >> 16);
}

// 4x f32 -> 4x bf16 via v_cvt_pk_bf16_f32 (RNE), 2 instructions
__device__ __forceinline__ s16x4 pack_bf16x4(float a, float b, float c, float d) {
    unsigned r0, r1;
    asm("v_cvt_pk_bf16_f32 %0, %1, %2" : "=v"(r0) : "v"(a), "v"(b));
    asm("v_cvt_pk_bf16_f32 %0, %1, %2" : "=v"(r1) : "v"(c), "v"(d));
    u32x2 t; t[0] = r0; t[1] = r1;
    return __builtin_bit_cast(s16x4, t);
}

__device__ __forceinline__ void gload16(const void* g, void* l) {
    __builtin_amdgcn_global_load_lds(
        (const __attribute__((address_space(1))) void*)g,
        (__attribute__((address_space(3))) void*)l, 16, 0, 0);
}

__device__ __forceinline__ f32x4 mfma_16x16x16(s16x4 a, s16x4 b, f32x4 c) {
#if __has_builtin(__builtin_amdgcn_mfma_f32_16x16x16bf16_1k)
    return __builtin_amdgcn_mfma_f32_16x16x16bf16_1k(a, b, c, 0, 0, 0);
#else
    asm("v_mfma_f32_16x16x16_bf16 %0, %1, %2, %0" : "+v"(c) : "v"(a), "v"(b));
    return c;
#endif
}

// ---------------------------------------------------------------------------
// x fp32 -> bf16, 8 elems/thread
__global__ __launch_bounds__(256) void cast_x_kernel(
    const float* __restrict__ in, unsigned short* __restrict__ out)
{
    const size_t i = (size_t)blockIdx.x * 256 + threadIdx.x;
    const float4* p = (const float4*)in;
    float4 a = p[2 * i], b = p[2 * i + 1];
    short8 o;
    o[0] = (short)f2bf(a.x); o[1] = (short)f2bf(a.y);
    o[2] = (short)f2bf(a.z); o[3] = (short)f2bf(a.w);
    o[4] = (short)f2bf(b.x); o[5] = (short)f2bf(b.y);
    o[6] = (short)f2bf(b.z); o[7] = (short)f2bf(b.w);
    *(short8*)(out + 8 * i) = o;
}

// W[k][n] fp32 -> Wt[n][k] bf16 (32x32 tiles), 4 matrices via blockIdx.z
__global__ __launch_bounds__(256) void transpose_cast_w(
    const float* __restrict__ W0, const float* __restrict__ W1,
    const float* __restrict__ W2, const float* __restrict__ W3,
    unsigned short* __restrict__ T0, unsigned short* __restrict__ T1,
    unsigned short* __restrict__ T2, unsigned short* __restrict__ T3)
{
    const int z = blockIdx.z;
    const float* W = (z == 0) ? W0 : (z == 1) ? W1 : (z == 2) ? W2 : W3;
    unsigned short* Wt = (z == 0) ? T0 : (z == 1) ? T1 : (z == 2) ? T2 : T3;

    __shared__ float tile[32][33];
    const int t = threadIdx.x;
    const int r0 = blockIdx.y * 32, c0 = blockIdx.x * 32;
    {
        const int r = t >> 3, c4 = (t & 7) * 4;
        float4 a = *(const float4*)&W[(size_t)(r0 + r) * 1024 + c0 + c4];
        tile[r][c4 + 0] = a.x; tile[r][c4 + 1] = a.y;
        tile[r][c4 + 2] = a.z; tile[r][c4 + 3] = a.w;
    }
    __syncthreads();
    {
        const int n = t >> 3, k4 = (t & 7) * 4;
        u16x4 o;
        o[0] = f2bf(tile[k4 + 0][n]); o[1] = f2bf(tile[k4 + 1][n]);
        o[2] = f2bf(tile[k4 + 2][n]); o[3] = f2bf(tile[k4 + 3][n]);
        *(u16x4*)&Wt[(size_t)(c0 + n) * 1024 + r0 + k4] = o;
    }
}

// ---------------------------------------------------------------------------
// GEMM: X[M,1024]bf16 @ Wt[n][k]bf16 + bias. 128x128 tile, BK=32, 4 waves,
// double-buffered global_load_lds staging, 1D grid + XCD-chunk swizzle (T1).
// FUSED=1: N=3072 (wq|wk|wv). cols 0-1023 -> Q bf16 [b,h,s,64]*qscale;
//   1024-2047 -> K bf16 [b,h,s,64]; 2048-3071 -> V bf16 [b,h,d,s] with
//   d-bit3 half-granule swap (s ^= 4 when d&8) for attn PV bank spread.
// FUSED=0: dst fp32 [M,1024] (output projection), grid-x width 8.
template <int FUSED>
__global__ __launch_bounds__(256) void gemm_bf16(
    const unsigned short* __restrict__ X, const unsigned short* __restrict__ Wt,
    const float* __restrict__ bias_q, const float* __restrict__ bias_k,
    const float* __restrict__ bias_v,
    void* __restrict__ dq, void* __restrict__ dk, void* __restrict__ dv,
    float qscale)
{
    constexpr int GX  = (FUSED == 1) ? 24 : 8;     // col-tiles
    constexpr int NWG = GX * 64;                   // total blocks (nwg%8==0)

    __shared__ __align__(16) unsigned short As[2][128 * 32];  // [buf][row][k]
    __shared__ __align__(16) unsigned short Bs[2][128 * 32];  // [buf][n][k]

    const int t = threadIdx.x;
    const int lane = t & 63, w = t >> 6;
    const int wr = w >> 1, wc = w & 1;
    const int l15 = lane & 15, lhi = lane >> 4;

    // T1 XCD swizzle: XCD (launched%8) owns contiguous orig chunk -> X-panel
    // L2 reuse across its GX column blocks.
    const int L = blockIdx.x;
    const int orig = (L & 7) * (NWG / 8) + (L >> 3);
    const int row0 = (orig / GX) * 128, col0 = (orig % GX) * 128;

    const f32x4 z = {0.f, 0.f, 0.f, 0.f};
    f32x4 acc[4][4];
    #pragma unroll
    for (int i = 0; i < 4; ++i)
        #pragma unroll
        for (int j = 0; j < 4; ++j) acc[i][j] = z;

    const int fchunk = ((lhi ^ ((l15 >> 1) & 3)) << 4);  // byte offset in 64B row

    auto STAGE = [&](int buf, int k0) {
        #pragma unroll
        for (int i = 0; i < 2; ++i) {
            int seg = t + i * 256;
            int row = seg >> 2;
            int ch  = (seg & 3) ^ ((row >> 1) & 3);  // pre-swizzled global source
            gload16(X  + (size_t)(row0 + row) * 1024 + k0 + ch * 8,
                    (char*)As[buf] + seg * 16);
            gload16(Wt + (size_t)(col0 + row) * 1024 + k0 + ch * 8,
                    (char*)Bs[buf] + seg * 16);
        }
    };

    STAGE(0, 0);
    for (int k0 = 0; k0 < 1024; k0 += 32) {
        const int cur = (k0 >> 5) & 1;
        __syncthreads();  // drains prefetch (vmcnt) + protects buf cur^1 reads
        if (k0 + 32 < 1024) STAGE(cur ^ 1, k0 + 32);

        short8 a[4], b[4];
        #pragma unroll
        for (int mi = 0; mi < 4; ++mi)
            a[mi] = *(const short8*)((const char*)As[cur]
                + (wr * 64 + mi * 16 + l15) * 64 + fchunk);
        #pragma unroll
        for (int ni = 0; ni < 4; ++ni)
            b[ni] = *(const short8*)((const char*)Bs[cur]
                + (wc * 64 + ni * 16 + l15) * 64 + fchunk);
        #pragma unroll
        for (int mi = 0; mi < 4; ++mi)
            #pragma unroll
            for (int ni = 0; ni < 4; ++ni)
                acc[mi][ni] = __builtin_amdgcn_mfma_f32_16x16x32_bf16(
                    a[mi], b[ni], acc[mi][ni], 0, 0, 0);
    }

    #pragma unroll
    for (int mi = 0; mi < 4; ++mi)
        #pragma unroll
        for (int ni = 0; ni < 4; ++ni) {
            const int cc = col0 + wc * 64 + ni * 16 + l15;
            if constexpr (FUSED == 1) {
                const int sel = cc >> 10;          // 0=Q 1=K 2=V, uniform/block
                const int hh = (cc >> 6) & 15, dd = cc & 63;
                const float bv = (sel == 0 ? bias_q : sel == 1 ? bias_k : bias_v)
                                 [cc & 1023];
                const int rr0 = row0 + wr * 64 + mi * 16 + lhi * 4;
                const int b0i = rr0 >> 11, s0_ = rr0 & 2047;
                if (sel == 2) {
                    // V^T [b,h,d,s] with half-granule swap: s ^= 4 when d&8
                    const int sstore = s0_ ^ (((cc >> 3) & 1) << 2);
                    s16x4 pv = pack_bf16x4(
                        acc[mi][ni][0] + bv, acc[mi][ni][1] + bv,
                        acc[mi][ni][2] + bv, acc[mi][ni][3] + bv);
                    *(s16x4*)&((unsigned short*)dv)[
                        (((size_t)(b0i * 16 + hh) * 64 + dd) << 11) + sstore] = pv;
                } else {
                    unsigned short* dst = (unsigned short*)(sel == 0 ? dq : dk);
                    const float sc_ = (sel == 0) ? qscale : 1.0f;
                    #pragma unroll
                    for (int r = 0; r < 4; ++r)
                        dst[(((size_t)(b0i * 16 + hh) * 2048 + s0_ + r) << 6) + dd]
                            = f2bf((acc[mi][ni][r] + bv) * sc_);
                }
            } else {
                const float bv = bias_q[cc];
                #pragma unroll
                for (int r = 0; r < 4; ++r) {
                    const int rr = row0 + wr * 64 + mi * 16 + lhi * 4 + r;
                    ((float*)dq)[(size_t)rr * 1024 + cc] = acc[mi][ni][r] + bv;
                }
            }
        }
}

// ---------------------------------------------------------------------------
// Flash causal attention v4. Q,K [b,h,s,64] (Q pre-scaled by 0.125*log2e),
// Vt [b,h,d,s] with d-bit3 half-swap. Out bf16 [b,s,h*64+d] == [M,1024].
// 256 thr = 4 waves, q-tile 256 (64 q/wave as 4x16), kv-tile 64, dbuf.
// Swapped QK^T (lane q=l15 owns softmax row), in-reg softmax w/ defer-max,
// cvt_pk P-packing, PV via 16x16x16 MFMA (P never in LDS), T5 setprio.
// Grid 512: bh = id&63 (K/V L2 share); bx paired so CU pair {id,id+256}
// sums to constant causal depth (36 iters).
__global__ __launch_bounds__(256) void attn_mfma(
    const unsigned short* __restrict__ Q, const unsigned short* __restrict__ K,
    const unsigned short* __restrict__ Vt, unsigned short* __restrict__ Out)
{
    __shared__ __align__(16) unsigned short Ks[2][64 * 64];  // [buf][kv][d] swz
    __shared__ __align__(16) unsigned short Vs[2][64 * 64];  // [buf][d][kv] swz

    const int t = threadIdx.x, lane = t & 63, w = t >> 6;
    const int l15 = lane & 15, lhi = lane >> 4;
    const int id = blockIdx.x;
    int bx = (id >> 6) & 3;
    if (id & 256) bx = 7 - bx;           // pair bx with 7-bx per CU slot
    const int bh = id & 63;
    const int q0 = bx * 256;
    const size_t base = (size_t)bh * S * 64;

    // Q as B-operand fragments: col=q=l15, k=d
    short8 bq[4][2];
    #pragma unroll
    for (int mi = 0; mi < 4; ++mi)
        #pragma unroll
        for (int ks = 0; ks < 2; ++ks)
            bq[mi][ks] = *(const short8*)(Q + base
                + (size_t)(q0 + w * 64 + mi * 16 + l15) * 64 + ks * 32 + lhi * 8);

    const f32x4 z = {0.f, 0.f, 0.f, 0.f};
    f32x4 o[4][4];  // [mi][dblk]; rows d=dblk*16+lhi*4+r, col q=l15
    float mrow[4] = {-INFINITY, -INFINITY, -INFINITY, -INFINITY};
    float lrow[4] = {0.f, 0.f, 0.f, 0.f};
    #pragma unroll
    for (int mi = 0; mi < 4; ++mi)
        #pragma unroll
        for (int d = 0; d < 4; ++d) o[mi][d] = z;

    auto STAGE = [&](int buf, int kt) {
        const int k0 = kt * 64;
        #pragma unroll
        for (int i = 0; i < 2; ++i) {
            int seg = t + i * 256;
            int row = seg >> 3;
            int ch  = (seg & 7) ^ (row & 7);  // pre-swizzled source
            gload16(K + base + (size_t)(k0 + row) * 64 + ch * 8,
                    (char*)Ks[buf] + seg * 16);
            gload16(Vt + ((size_t)bh * 64 + row) * S + k0 + ch * 8,
                    (char*)Vs[buf] + seg * 16);
        }
    };

    const int ntiles = 4 * bx + 4;  // causal, q-tile 256
    STAGE(0, 0);
    __syncthreads();

    for (int kt = 0; kt < ntiles; ++kt) {
        const int cur = kt & 1;
        const int k0 = kt * 64;
        if (kt + 1 < ntiles) STAGE(cur ^ 1, kt + 1);

        // QK^T swapped: rows kv, col q
        f32x4 sc[4][4];
        #pragma unroll
        for (int mi = 0; mi < 4; ++mi)
            #pragma unroll
            for (int ni = 0; ni < 4; ++ni) sc[mi][ni] = z;
        __builtin_amdgcn_s_setprio(1);
        #pragma unroll
        for (int ks = 0; ks < 2; ++ks)
            #pragma unroll
            for (int ni = 0; ni < 4; ++ni) {
                short8 ak = *(const short8*)((const char*)Ks[cur]
                    + (ni * 16 + l15) * 128 + (((ks * 4 + lhi) ^ (l15 & 7)) << 4));
                #pragma unroll
                for (int mi = 0; mi < 4; ++mi)
                    sc[mi][ni] = __builtin_amdgcn_mfma_f32_16x16x32_bf16(
                        ak, bq[mi][ks], sc[mi][ni], 0, 0, 0);
            }
        __builtin_amdgcn_s_setprio(0);

        if (k0 >= q0) {  // diagonal-overlap tiles
            #pragma unroll
            for (int mi = 0; mi < 4; ++mi) {
                const int qg = q0 + w * 64 + mi * 16 + l15;
                #pragma unroll
                for (int ni = 0; ni < 4; ++ni)
                    #pragma unroll
                    for (int r = 0; r < 4; ++r)
                        if (k0 + ni * 16 + lhi * 4 + r > qg)
                            sc[mi][ni][r] = -INFINITY;
            }
        }

        // in-register online softmax (exp2 domain) + defer-max + cvt_pk pack
        s16x4 pf[4][4];
        #pragma unroll
        for (int mi = 0; mi < 4; ++mi) {
            float tm = -INFINITY;
            #pragma unroll
            for (int ni = 0; ni < 4; ++ni) {
                float a0 = fmaxf(sc[mi][ni][0], sc[mi][ni][1]);
                float a1 = fmaxf(sc[mi][ni][2], sc[mi][ni][3]);
                tm = fmaxf(tm, fmaxf(a0, a1));
            }
            tm = fmaxf(tm, __shfl_xor(tm, 16));
            tm = fmaxf(tm, __shfl_xor(tm, 32));
            // defer-max (T13): rescale only if some lane grew by >8 (2^8 bound)
            if (!__all(tm <= mrow[mi] + 8.f)) {
                const float mnew = fmaxf(mrow[mi], tm);
                const float alpha = exp2f(mrow[mi] - mnew);
                mrow[mi] = mnew;
                lrow[mi] *= alpha;
                #pragma unroll
                for (int d = 0; d < 4; ++d) {
                    o[mi][d][0] *= alpha; o[mi][d][1] *= alpha;
                    o[mi][d][2] *= alpha; o[mi][d][3] *= alpha;
                }
            }
            float ps = 0.f;
            #pragma unroll
            for (int ni = 0; ni < 4; ++ni) {
                float p0 = exp2f(sc[mi][ni][0] - mrow[mi]);
                float p1 = exp2f(sc[mi][ni][1] - mrow[mi]);
                float p2 = exp2f(sc[mi][ni][2] - mrow[mi]);
                float p3 = exp2f(sc[mi][ni][3] - mrow[mi]);
                ps += (p0 + p1) + (p2 + p3);
                pf[mi][ni] = pack_bf16x4(p0, p1, p2, p3);
            }
            ps += __shfl_xor(ps, 16);
            ps += __shfl_xor(ps, 32);
            lrow[mi] += ps;
        }

        // PV swapped: O^T[d][q] += V^T[d][kv] @ P^T[kv][q]
        // half-swap read: half = (lhi&1) ^ (l15>>3) -> 32-bank coverage
        __builtin_amdgcn_s_setprio(1);
        #pragma unroll
        for (int ni = 0; ni < 4; ++ni) {
            #pragma unroll
            for (int db = 0; db < 4; ++db) {
                const int row = db * 16 + l15;
                const int slot = ((ni * 2 + (lhi >> 1)) ^ (l15 & 7));
                const int half = (lhi & 1) ^ ((l15 >> 3) & 1);
                s16x4 av = *(const s16x4*)((const char*)Vs[cur]
                    + row * 128 + slot * 16 + half * 8);
                #pragma unroll
                for (int mi = 0; mi < 4; ++mi)
                    o[mi][db] = mfma_16x16x16(av, pf[mi][ni], o[mi][db]);
            }
        }
        __builtin_amdgcn_s_setprio(0);

        __syncthreads();  // next tile staged; buffers safe to swap
    }

    // normalize + store bf16 to [b, s, h*64+d]; lane q=l15
    const int b_ = bh >> 4, h_ = bh & 15;
    #pragma unroll
    for (int mi = 0; mi < 4; ++mi) {
        const float inv = 1.0f / lrow[mi];
        const int s_ = q0 + w * 64 + mi * 16 + l15;
        #pragma unroll
        for (int db = 0; db < 4; ++db) {
            s16x4 ov = pack_bf16x4(o[mi][db][0] * inv, o[mi][db][1] * inv,
                                   o[mi][db][2] * inv, o[mi][db][3] * inv);
            *(s16x4*)&Out[(size_t)(b_ * S + s_) * 1024 + h_ * 64 + db * 16 + lhi * 4]
                = ov;
        }
    }
}

// ---------------------------------------------------------------------------
extern "C" void kernel_launch(void* const* d_in, const int* in_sizes, int n_in,
                              void* d_out, int out_size, void* d_ws, size_t ws_size,
                              hipStream_t stream)
{
    const float* x  = (const float*)d_in[0];
    // d_in[1] = attn_mask — causal, handled analytically
    const float* Wq = (const float*)d_in[2];
    const float* bq = (const float*)d_in[3];
    const float* Wk = (const float*)d_in[4];
    const float* bk = (const float*)d_in[5];
    const float* Wv = (const float*)d_in[6];
    const float* bv = (const float*)d_in[7];
    const float* Wo = (const float*)d_in[8];
    const float* bo = (const float*)d_in[9];
    float* out = (float*)d_out;

    unsigned short* p = (unsigned short*)d_ws;
    unsigned short* xb  = p; p += (size_t)M * DM;
    unsigned short* wqt = p; p += (size_t)DM * DM;   // wqt|wkt|wvt contiguous
    unsigned short* wkt = p; p += (size_t)DM * DM;
    unsigned short* wvt = p; p += (size_t)DM * DM;
    unsigned short* wot = p; p += (size_t)DM * DM;
    unsigned short* qb  = p; p += (size_t)M * DM;
    unsigned short* kb  = p; p += (size_t)M * DM;
    unsigned short* vtb = p; p += (size_t)M * DM;
    unsigned short* attnb = p;

    cast_x_kernel<<<M * DM / 8 / 256, 256, 0, stream>>>(x, xb);
    transpose_cast_w<<<dim3(32, 32, 4), 256, 0, stream>>>(
        Wq, Wk, Wv, Wo, wqt, wkt, wvt, wot);

    // fold 1/sqrt(dk) * log2(e) into Q so softmax runs in exp2 domain
    const float qscale = 0.125f * 1.44269504088896340736f;
    gemm_bf16<1><<<dim3(24 * 64), 256, 0, stream>>>(
        xb, wqt, bq, bk, bv, qb, kb, vtb, qscale);

    attn_mfma<<<dim3(512), 256, 0, stream>>>(qb, kb, vtb, attnb);

    gemm_bf16<0><<<dim3(8 * 64), 256, 0, stream>>>(
        attnb, wot, bo, nullptr, nullptr, out, nullptr, nullptr, 1.0f);
}

// Round 8
// 296.004 us; speedup vs baseline: 1.1190x; 1.1190x over previous
//
#include <hip/hip_runtime.h>
#include <math.h>

// MultiHeadAttn bf16-MFMA pipeline for MI355X (gfx950), round 8.
// r8: attn reverted to QBLK=128 (r7's QBLK=256 hit the VGPR/occupancy cliff:
// 180 VGPR -> 2 waves/SIMD -> 135us vs 117us). New: balanced causal-depth
// pairing (bx<->15-bx) so each CU's 4 resident blocks sum to constant 68
// tile-iters; setprio kept around MFMA clusters. GEMMs unchanged from r6.

typedef __attribute__((ext_vector_type(8))) short short8;   // 8 bf16 = 4 VGPR
typedef __attribute__((ext_vector_type(4))) short s16x4;    // 4 bf16 = 2 VGPR
typedef __attribute__((ext_vector_type(4))) float f32x4;    // MFMA C/D
typedef __attribute__((ext_vector_type(4))) unsigned short u16x4;
typedef __attribute__((ext_vector_type(2))) unsigned int u32x2;

constexpr int B  = 4;
constexpr int S  = 2048;
constexpr int H  = 16;
constexpr int DM = 1024;
constexpr int M  = B * S;  // 8192

__device__ __forceinline__ unsigned short f2bf(float f) {
    union { float f; unsigned u; } v; v.f = f;
    unsigned r = v.u + 0x7FFFu + ((v.u >> 16) & 1u);  // RNE, finite inputs
    return (unsigned short)(r >> 16);
}

// 4x f32 -> 4x bf16 via v_cvt_pk_bf16_f32 (RNE), 2 instructions
__device__ __forceinline__ s16x4 pack_bf16x4(float a, float b, float c, float d) {
    unsigned r0, r1;
    asm("v_cvt_pk_bf16_f32 %0, %1, %2" : "=v"(r0) : "v"(a), "v"(b));
    asm("v_cvt_pk_bf16_f32 %0, %1, %2" : "=v"(r1) : "v"(c), "v"(d));
    u32x2 t; t[0] = r0; t[1] = r1;
    return __builtin_bit_cast(s16x4, t);
}

__device__ __forceinline__ void gload16(const void* g, void* l) {
    __builtin_amdgcn_global_load_lds(
        (const __attribute__((address_space(1))) void*)g,
        (__attribute__((address_space(3))) void*)l, 16, 0, 0);
}

__device__ __forceinline__ f32x4 mfma_16x16x16(s16x4 a, s16x4 b, f32x4 c) {
#if __has_builtin(__builtin_amdgcn_mfma_f32_16x16x16bf16_1k)
    return __builtin_amdgcn_mfma_f32_16x16x16bf16_1k(a, b, c, 0, 0, 0);
#else
    asm("v_mfma_f32_16x16x16_bf16 %0, %1, %2, %0" : "+v"(c) : "v"(a), "v"(b));
    return c;
#endif
}

// ---------------------------------------------------------------------------
// x fp32 -> bf16, 8 elems/thread
__global__ __launch_bounds__(256) void cast_x_kernel(
    const float* __restrict__ in, unsigned short* __restrict__ out)
{
    const size_t i = (size_t)blockIdx.x * 256 + threadIdx.x;
    const float4* p = (const float4*)in;
    float4 a = p[2 * i], b = p[2 * i + 1];
    short8 o;
    o[0] = (short)f2bf(a.x); o[1] = (short)f2bf(a.y);
    o[2] = (short)f2bf(a.z); o[3] = (short)f2bf(a.w);
    o[4] = (short)f2bf(b.x); o[5] = (short)f2bf(b.y);
    o[6] = (short)f2bf(b.z); o[7] = (short)f2bf(b.w);
    *(short8*)(out + 8 * i) = o;
}

// W[k][n] fp32 -> Wt[n][k] bf16 (32x32 tiles), 4 matrices via blockIdx.z
__global__ __launch_bounds__(256) void transpose_cast_w(
    const float* __restrict__ W0, const float* __restrict__ W1,
    const float* __restrict__ W2, const float* __restrict__ W3,
    unsigned short* __restrict__ T0, unsigned short* __restrict__ T1,
    unsigned short* __restrict__ T2, unsigned short* __restrict__ T3)
{
    const int z = blockIdx.z;
    const float* W = (z == 0) ? W0 : (z == 1) ? W1 : (z == 2) ? W2 : W3;
    unsigned short* Wt = (z == 0) ? T0 : (z == 1) ? T1 : (z == 2) ? T2 : T3;

    __shared__ float tile[32][33];
    const int t = threadIdx.x;
    const int r0 = blockIdx.y * 32, c0 = blockIdx.x * 32;
    {
        const int r = t >> 3, c4 = (t & 7) * 4;
        float4 a = *(const float4*)&W[(size_t)(r0 + r) * 1024 + c0 + c4];
        tile[r][c4 + 0] = a.x; tile[r][c4 + 1] = a.y;
        tile[r][c4 + 2] = a.z; tile[r][c4 + 3] = a.w;
    }
    __syncthreads();
    {
        const int n = t >> 3, k4 = (t & 7) * 4;
        u16x4 o;
        o[0] = f2bf(tile[k4 + 0][n]); o[1] = f2bf(tile[k4 + 1][n]);
        o[2] = f2bf(tile[k4 + 2][n]); o[3] = f2bf(tile[k4 + 3][n]);
        *(u16x4*)&Wt[(size_t)(c0 + n) * 1024 + r0 + k4] = o;
    }
}

// ---------------------------------------------------------------------------
// GEMM: X[M,1024]bf16 @ Wt[n][k]bf16 + bias. 128x128 tile, BK=32, 4 waves,
// double-buffered global_load_lds staging, 1D grid + XCD-chunk swizzle (T1).
// FUSED=1: N=3072 (wq|wk|wv). cols 0-1023 -> Q bf16 [b,h,s,64]*qscale;
//   1024-2047 -> K bf16 [b,h,s,64]; 2048-3071 -> V bf16 [b,h,d,s] with
//   d-bit3 half-granule swap (s ^= 4 when d&8) for attn PV bank spread.
// FUSED=0: dst fp32 [M,1024] (output projection), grid-x width 8.
template <int FUSED>
__global__ __launch_bounds__(256) void gemm_bf16(
    const unsigned short* __restrict__ X, const unsigned short* __restrict__ Wt,
    const float* __restrict__ bias_q, const float* __restrict__ bias_k,
    const float* __restrict__ bias_v,
    void* __restrict__ dq, void* __restrict__ dk, void* __restrict__ dv,
    float qscale)
{
    constexpr int GX  = (FUSED == 1) ? 24 : 8;     // col-tiles
    constexpr int NWG = GX * 64;                   // total blocks (nwg%8==0)

    __shared__ __align__(16) unsigned short As[2][128 * 32];  // [buf][row][k]
    __shared__ __align__(16) unsigned short Bs[2][128 * 32];  // [buf][n][k]

    const int t = threadIdx.x;
    const int lane = t & 63, w = t >> 6;
    const int wr = w >> 1, wc = w & 1;
    const int l15 = lane & 15, lhi = lane >> 4;

    // T1 XCD swizzle: XCD (launched%8) owns contiguous orig chunk -> X-panel
    // L2 reuse across its GX column blocks.
    const int L = blockIdx.x;
    const int orig = (L & 7) * (NWG / 8) + (L >> 3);
    const int row0 = (orig / GX) * 128, col0 = (orig % GX) * 128;

    const f32x4 z = {0.f, 0.f, 0.f, 0.f};
    f32x4 acc[4][4];
    #pragma unroll
    for (int i = 0; i < 4; ++i)
        #pragma unroll
        for (int j = 0; j < 4; ++j) acc[i][j] = z;

    const int fchunk = ((lhi ^ ((l15 >> 1) & 3)) << 4);  // byte offset in 64B row

    auto STAGE = [&](int buf, int k0) {
        #pragma unroll
        for (int i = 0; i < 2; ++i) {
            int seg = t + i * 256;
            int row = seg >> 2;
            int ch  = (seg & 3) ^ ((row >> 1) & 3);  // pre-swizzled global source
            gload16(X  + (size_t)(row0 + row) * 1024 + k0 + ch * 8,
                    (char*)As[buf] + seg * 16);
            gload16(Wt + (size_t)(col0 + row) * 1024 + k0 + ch * 8,
                    (char*)Bs[buf] + seg * 16);
        }
    };

    STAGE(0, 0);
    for (int k0 = 0; k0 < 1024; k0 += 32) {
        const int cur = (k0 >> 5) & 1;
        __syncthreads();  // drains prefetch (vmcnt) + protects buf cur^1 reads
        if (k0 + 32 < 1024) STAGE(cur ^ 1, k0 + 32);

        short8 a[4], b[4];
        #pragma unroll
        for (int mi = 0; mi < 4; ++mi)
            a[mi] = *(const short8*)((const char*)As[cur]
                + (wr * 64 + mi * 16 + l15) * 64 + fchunk);
        #pragma unroll
        for (int ni = 0; ni < 4; ++ni)
            b[ni] = *(const short8*)((const char*)Bs[cur]
                + (wc * 64 + ni * 16 + l15) * 64 + fchunk);
        #pragma unroll
        for (int mi = 0; mi < 4; ++mi)
            #pragma unroll
            for (int ni = 0; ni < 4; ++ni)
                acc[mi][ni] = __builtin_amdgcn_mfma_f32_16x16x32_bf16(
                    a[mi], b[ni], acc[mi][ni], 0, 0, 0);
    }

    #pragma unroll
    for (int mi = 0; mi < 4; ++mi)
        #pragma unroll
        for (int ni = 0; ni < 4; ++ni) {
            const int cc = col0 + wc * 64 + ni * 16 + l15;
            if constexpr (FUSED == 1) {
                const int sel = cc >> 10;          // 0=Q 1=K 2=V, uniform/block
                const int hh = (cc >> 6) & 15, dd = cc & 63;
                const float bv = (sel == 0 ? bias_q : sel == 1 ? bias_k : bias_v)
                                 [cc & 1023];
                const int rr0 = row0 + wr * 64 + mi * 16 + lhi * 4;
                const int b0i = rr0 >> 11, s0_ = rr0 & 2047;
                if (sel == 2) {
                    // V^T [b,h,d,s] with half-granule swap: s ^= 4 when d&8
                    const int sstore = s0_ ^ (((cc >> 3) & 1) << 2);
                    s16x4 pv = pack_bf16x4(
                        acc[mi][ni][0] + bv, acc[mi][ni][1] + bv,
                        acc[mi][ni][2] + bv, acc[mi][ni][3] + bv);
                    *(s16x4*)&((unsigned short*)dv)[
                        (((size_t)(b0i * 16 + hh) * 64 + dd) << 11) + sstore] = pv;
                } else {
                    unsigned short* dst = (unsigned short*)(sel == 0 ? dq : dk);
                    const float sc_ = (sel == 0) ? qscale : 1.0f;
                    #pragma unroll
                    for (int r = 0; r < 4; ++r)
                        dst[(((size_t)(b0i * 16 + hh) * 2048 + s0_ + r) << 6) + dd]
                            = f2bf((acc[mi][ni][r] + bv) * sc_);
                }
            } else {
                const float bv = bias_q[cc];
                #pragma unroll
                for (int r = 0; r < 4; ++r) {
                    const int rr = row0 + wr * 64 + mi * 16 + lhi * 4 + r;
                    ((float*)dq)[(size_t)rr * 1024 + cc] = acc[mi][ni][r] + bv;
                }
            }
        }
}

// ---------------------------------------------------------------------------
// Flash causal attention v5 (= r5 structure + depth-balanced grid).
// Q,K [b,h,s,64] (Q pre-scaled by 0.125*log2e), Vt [b,h,d,s] w/ d-bit3
// half-swap. Out bf16 [b,s,h*64+d] == [M,1024].
// 256 thr = 4 waves, q-tile 128 (32 q/wave), kv-tile 64, dbuf staging.
// Swapped QK^T (lane q=l15 owns softmax row), in-reg softmax w/ defer-max,
// cvt_pk P-packing, PV via 16x16x16 MFMA (P never in LDS), T5 setprio.
// Grid 1024: bh=id&63 (K/V L2 share); j=id>>6, bx = j<8 ? j : 15-(j&7) so
// each CU's 4 resident blocks have constant total causal depth (68 iters).
__global__ __launch_bounds__(256) void attn_mfma(
    const unsigned short* __restrict__ Q, const unsigned short* __restrict__ K,
    const unsigned short* __restrict__ Vt, unsigned short* __restrict__ Out)
{
    __shared__ __align__(16) unsigned short Ks[2][64 * 64];  // [buf][kv][d] swz
    __shared__ __align__(16) unsigned short Vs[2][64 * 64];  // [buf][d][kv] swz

    const int t = threadIdx.x, lane = t & 63, w = t >> 6;
    const int l15 = lane & 15, lhi = lane >> 4;
    const int id = blockIdx.x;
    const int j = id >> 6;
    const int bx = (j < 8) ? j : 15 - (j & 7);   // depth-balanced pairing
    const int bh = id & 63;
    const int q0 = bx * 128;
    const size_t base = (size_t)bh * S * 64;

    // Q as B-operand fragments: col=q=l15, k=d
    short8 bq[2][2];
    #pragma unroll
    for (int mi = 0; mi < 2; ++mi)
        #pragma unroll
        for (int ks = 0; ks < 2; ++ks)
            bq[mi][ks] = *(const short8*)(Q + base
                + (size_t)(q0 + w * 32 + mi * 16 + l15) * 64 + ks * 32 + lhi * 8);

    const f32x4 z = {0.f, 0.f, 0.f, 0.f};
    f32x4 o[2][4];  // [mi][dblk]; rows d=dblk*16+lhi*4+r, col q=l15
    float mrow[2] = {-INFINITY, -INFINITY}, lrow[2] = {0.f, 0.f};
    #pragma unroll
    for (int mi = 0; mi < 2; ++mi)
        #pragma unroll
        for (int d = 0; d < 4; ++d) o[mi][d] = z;

    auto STAGE = [&](int buf, int kt) {
        const int k0 = kt * 64;
        #pragma unroll
        for (int i = 0; i < 2; ++i) {
            int seg = t + i * 256;
            int row = seg >> 3;
            int ch  = (seg & 7) ^ (row & 7);  // pre-swizzled source
            gload16(K + base + (size_t)(k0 + row) * 64 + ch * 8,
                    (char*)Ks[buf] + seg * 16);
            gload16(Vt + ((size_t)bh * 64 + row) * S + k0 + ch * 8,
                    (char*)Vs[buf] + seg * 16);
        }
    };

    const int ntiles = 2 * bx + 2;  // causal
    STAGE(0, 0);
    __syncthreads();

    for (int kt = 0; kt < ntiles; ++kt) {
        const int cur = kt & 1;
        const int k0 = kt * 64;
        if (kt + 1 < ntiles) STAGE(cur ^ 1, kt + 1);

        // QK^T swapped: rows kv, col q
        f32x4 sc[2][4];
        #pragma unroll
        for (int mi = 0; mi < 2; ++mi)
            #pragma unroll
            for (int ni = 0; ni < 4; ++ni) sc[mi][ni] = z;
        __builtin_amdgcn_s_setprio(1);
        #pragma unroll
        for (int ks = 0; ks < 2; ++ks)
            #pragma unroll
            for (int ni = 0; ni < 4; ++ni) {
                short8 ak = *(const short8*)((const char*)Ks[cur]
                    + (ni * 16 + l15) * 128 + (((ks * 4 + lhi) ^ (l15 & 7)) << 4));
                #pragma unroll
                for (int mi = 0; mi < 2; ++mi)
                    sc[mi][ni] = __builtin_amdgcn_mfma_f32_16x16x32_bf16(
                        ak, bq[mi][ks], sc[mi][ni], 0, 0, 0);
            }
        __builtin_amdgcn_s_setprio(0);

        if (k0 >= q0) {  // diagonal-overlap tiles
            #pragma unroll
            for (int mi = 0; mi < 2; ++mi) {
                const int qg = q0 + w * 32 + mi * 16 + l15;
                #pragma unroll
                for (int ni = 0; ni < 4; ++ni)
                    #pragma unroll
                    for (int r = 0; r < 4; ++r)
                        if (k0 + ni * 16 + lhi * 4 + r > qg)
                            sc[mi][ni][r] = -INFINITY;
            }
        }

        // in-register online softmax (exp2 domain) + defer-max + cvt_pk pack
        s16x4 pf[2][4];
        #pragma unroll
        for (int mi = 0; mi < 2; ++mi) {
            float tm = -INFINITY;
            #pragma unroll
            for (int ni = 0; ni < 4; ++ni) {
                float a0 = fmaxf(sc[mi][ni][0], sc[mi][ni][1]);
                float a1 = fmaxf(sc[mi][ni][2], sc[mi][ni][3]);
                tm = fmaxf(tm, fmaxf(a0, a1));
            }
            tm = fmaxf(tm, __shfl_xor(tm, 16));
            tm = fmaxf(tm, __shfl_xor(tm, 32));
            // defer-max (T13): rescale only if some lane grew by >8 (2^8 bound)
            if (!__all(tm <= mrow[mi] + 8.f)) {
                const float mnew = fmaxf(mrow[mi], tm);
                const float alpha = exp2f(mrow[mi] - mnew);
                mrow[mi] = mnew;
                lrow[mi] *= alpha;
                #pragma unroll
                for (int d = 0; d < 4; ++d) {
                    o[mi][d][0] *= alpha; o[mi][d][1] *= alpha;
                    o[mi][d][2] *= alpha; o[mi][d][3] *= alpha;
                }
            }
            float ps = 0.f;
            #pragma unroll
            for (int ni = 0; ni < 4; ++ni) {
                float p0 = exp2f(sc[mi][ni][0] - mrow[mi]);
                float p1 = exp2f(sc[mi][ni][1] - mrow[mi]);
                float p2 = exp2f(sc[mi][ni][2] - mrow[mi]);
                float p3 = exp2f(sc[mi][ni][3] - mrow[mi]);
                ps += (p0 + p1) + (p2 + p3);
                pf[mi][ni] = pack_bf16x4(p0, p1, p2, p3);
            }
            ps += __shfl_xor(ps, 16);
            ps += __shfl_xor(ps, 32);
            lrow[mi] += ps;
        }

        // PV swapped: O^T[d][q] += V^T[d][kv] @ P^T[kv][q]
        // half-swap read: half = (lhi&1) ^ (l15>>3) -> 32-bank coverage
        __builtin_amdgcn_s_setprio(1);
        #pragma unroll
        for (int ni = 0; ni < 4; ++ni) {
            #pragma unroll
            for (int db = 0; db < 4; ++db) {
                const int row = db * 16 + l15;
                const int slot = ((ni * 2 + (lhi >> 1)) ^ (l15 & 7));
                const int half = (lhi & 1) ^ ((l15 >> 3) & 1);
                s16x4 av = *(const s16x4*)((const char*)Vs[cur]
                    + row * 128 + slot * 16 + half * 8);
                #pragma unroll
                for (int mi = 0; mi < 2; ++mi)
                    o[mi][db] = mfma_16x16x16(av, pf[mi][ni], o[mi][db]);
            }
        }
        __builtin_amdgcn_s_setprio(0);

        __syncthreads();  // next tile staged; buffers safe to swap
    }

    // normalize + store bf16 to [b, s, h*64+d]; lane q=l15
    const int b_ = bh >> 4, h_ = bh & 15;
    #pragma unroll
    for (int mi = 0; mi < 2; ++mi) {
        const float inv = 1.0f / lrow[mi];
        const int s_ = q0 + w * 32 + mi * 16 + l15;
        #pragma unroll
        for (int db = 0; db < 4; ++db) {
            s16x4 ov = pack_bf16x4(o[mi][db][0] * inv, o[mi][db][1] * inv,
                                   o[mi][db][2] * inv, o[mi][db][3] * inv);
            *(s16x4*)&Out[(size_t)(b_ * S + s_) * 1024 + h_ * 64 + db * 16 + lhi * 4]
                = ov;
        }
    }
}

// ---------------------------------------------------------------------------
extern "C" void kernel_launch(void* const* d_in, const int* in_sizes, int n_in,
                              void* d_out, int out_size, void* d_ws, size_t ws_size,
                              hipStream_t stream)
{
    const float* x  = (const float*)d_in[0];
    // d_in[1] = attn_mask — causal, handled analytically
    const float* Wq = (const float*)d_in[2];
    const float* bq = (const float*)d_in[3];
    const float* Wk = (const float*)d_in[4];
    const float* bk = (const float*)d_in[5];
    const float* Wv = (const float*)d_in[6];
    const float* bv = (const float*)d_in[7];
    const float* Wo = (const float*)d_in[8];
    const float* bo = (const float*)d_in[9];
    float* out = (float*)d_out;

    unsigned short* p = (unsigned short*)d_ws;
    unsigned short* xb  = p; p += (size_t)M * DM;
    unsigned short* wqt = p; p += (size_t)DM * DM;   // wqt|wkt|wvt contiguous
    unsigned short* wkt = p; p += (size_t)DM * DM;
    unsigned short* wvt = p; p += (size_t)DM * DM;
    unsigned short* wot = p; p += (size_t)DM * DM;
    unsigned short* qb  = p; p += (size_t)M * DM;
    unsigned short* kb  = p; p += (size_t)M * DM;
    unsigned short* vtb = p; p += (size_t)M * DM;
    unsigned short* attnb = p;

    cast_x_kernel<<<M * DM / 8 / 256, 256, 0, stream>>>(x, xb);
    transpose_cast_w<<<dim3(32, 32, 4), 256, 0, stream>>>(
        Wq, Wk, Wv, Wo, wqt, wkt, wvt, wot);

    // fold 1/sqrt(dk) * log2(e) into Q so softmax runs in exp2 domain
    const float qscale = 0.125f * 1.44269504088896340736f;
    gemm_bf16<1><<<dim3(24 * 64), 256, 0, stream>>>(
        xb, wqt, bq, bk, bv, qb, kb, vtb, qscale);

    attn_mfma<<<dim3(1024), 256, 0, stream>>>(qb, kb, vtb, attnb);

    gemm_bf16<0><<<dim3(8 * 64), 256, 0, stream>>>(
        attnb, wot, bo, nullptr, nullptr, out, nullptr, nullptr, 1.0f);
}